// Round 8
// baseline (263.053 us; speedup 1.0000x reference)
//
#include <hip/hip_runtime.h>
#include <stdint.h>

// Problem constants (fixed by the reference setup_inputs)
#define BATCH 128
#define SEQN  384
#define SEQM  384
#define DIM   128
#define KINF   1000000.0f                 // reference pseudo-infinity (nat units)
#define LOG2E  1.4426950408889634f
#define LN2    0.6931471805599453f
#define KINF2  (KINF * LOG2E)             // pseudo-infinity in base-2-scaled units

// hardware base-2 transcendentals (v_exp_f32 / v_log_f32)
#define EXP2F(x) __builtin_amdgcn_exp2f(x)
#define LOG2F(x) __builtin_amdgcn_logf(x)

typedef __attribute__((ext_vector_type(8))) short bf16x8;   // 8 bf16 = 4 VGPRs (MFMA A/B frag)
typedef __attribute__((ext_vector_type(4))) float f32x4;    // MFMA C/D frag

__device__ __forceinline__ unsigned short bf16_rne(float x) {
    uint32_t u = __float_as_uint(x);
    u += 0x7FFFu + ((u >> 16) & 1u);
    return (unsigned short)(u >> 16);
}
__device__ __forceinline__ uint32_t bf16_pair(float x, float y) {
    uint32_t ux = __float_as_uint(x); ux += 0x7FFFu + ((ux >> 16) & 1u);
    uint32_t uy = __float_as_uint(y); uy += 0x7FFFu + ((uy >> 16) & 1u);
    return (ux >> 16) | (uy & 0xFFFF0000u);
}

// ---------------------------------------------------------------------------
// Kernel 1: prep.  One wave per row: squared-norm (shuffle reduce) AND a
// bf16 copy of the row (so the GEMM phase does zero conversions).
// ---------------------------------------------------------------------------
__global__ __launch_bounds__(256) void prep_kernel(
        const float* __restrict__ a, const float* __restrict__ b,
        unsigned short* __restrict__ a16, unsigned short* __restrict__ b16,
        float* __restrict__ anorm, float* __restrict__ bnorm) {
    int wave = threadIdx.x >> 6;
    int lane = threadIdx.x & 63;
    long row = (long)blockIdx.x * 4 + wave;          // 0 .. 98303
    const long total = (long)BATCH * SEQN;           // 49152
    const float* src; unsigned short* d16; float* dst; long r;
    if (row < total) { src = a; d16 = a16; dst = anorm; r = row; }
    else             { src = b; d16 = b16; dst = bnorm; r = row - total; }
    float2 v = ((const float2*)(src + r * DIM))[lane];
    ((uint32_t*)(d16 + r * DIM))[lane] = bf16_pair(v.x, v.y);
    float s = v.x * v.x + v.y * v.y;
    #pragma unroll
    for (int off = 32; off > 0; off >>= 1) s += __shfl_down(s, off, 64);
    if (lane == 0) dst[r] = s;
}

// ---------------------------------------------------------------------------
// Kernel 2 (FUSED): one block per batch.
// Phase A (all 4 waves): Dt[j][i] = (anorm[i]+bnorm[j]-2*a_i.b_j)*LOG2E as
//   bf16, via 9 LDS-staged 128x128 MFMA tiles (round-7 tile body).  Dt is
//   per-batch (288 KB), written and read by THIS block only -> L2-resident.
// Phase B (wave 0): the skew-2 register-FIFO DP (round-6 body, unchanged).
// __syncthreads() guarantees block-scope visibility of phase-A global
// writes before phase B reads them.
// ---------------------------------------------------------------------------
__global__ __launch_bounds__(256) void fused_kernel(
        const unsigned short* __restrict__ a16, const unsigned short* __restrict__ b16,
        const float* __restrict__ anorm, const float* __restrict__ bnorm,
        unsigned short* __restrict__ DtG, float* __restrict__ out) {
    __shared__ unsigned short lds[2][128][128];      // 64 KB: [0]=A(i) [1]=B(j)
    const int batch = blockIdx.x;
    const int t = threadIdx.x;
    unsigned short* __restrict__ Dt = DtG + (long)batch * SEQM * SEQN;

    const int wave = t >> 6, lane = t & 63;
    const int iq = (wave & 1) * 64;                  // wave quadrant in tile
    const int jq = (wave >> 1) * 64;
    const int l16 = lane & 15, q = lane >> 4;

    // ---- Phase A: build Dt (9 tiles of 128x128) ----
    for (int it = 0; it < 3; it++) {
        for (int jt = 0; jt < 3; jt++) {
            const int i0 = it * 128, j0 = jt * 128;
            const unsigned short* asrc = a16 + ((long)batch * SEQN + i0) * DIM;
            const unsigned short* bsrc = b16 + ((long)batch * SEQM + j0) * DIM;
            __syncthreads();                         // lds reuse barrier
            #pragma unroll
            for (int p = 0; p < 8; p++) {            // stage 2x32 KB, coalesced
                int e   = p * 2048 + t * 8;
                int row = e >> 7;
                int grp = (e >> 3) & 15;
                uint4 va = *(const uint4*)(asrc + e);
                uint4 vb = *(const uint4*)(bsrc + e);
                int sw = (grp ^ (row & 15)) * 8;     // bank swizzle
                *(uint4*)&lds[0][row][sw] = va;
                *(uint4*)&lds[1][row][sw] = vb;
            }
            __syncthreads();

            f32x4 acc[4][4] = {};                    // [si (i-dir)][sj (j-dir)]
            #pragma unroll
            for (int kk = 0; kk < 4; kk++) {         // K = 4 * 32
                bf16x8 af[4], bfr[4];
                #pragma unroll
                for (int s = 0; s < 4; s++) {
                    int arow = iq + s * 16 + l16;
                    af[s]  = *(const bf16x8*)&lds[0][arow][((kk * 4 + q) ^ (arow & 15)) * 8];
                    int brow = jq + s * 16 + l16;
                    bfr[s] = *(const bf16x8*)&lds[1][brow][((kk * 4 + q) ^ (brow & 15)) * 8];
                }
                #pragma unroll
                for (int si = 0; si < 4; si++)
                    #pragma unroll
                    for (int sj = 0; sj < 4; sj++)
                        acc[si][sj] = __builtin_amdgcn_mfma_f32_16x16x32_bf16(
                                          af[si], bfr[sj], acc[si][sj], 0, 0, 0);
            }

            // epilogue: col j fixed per lane; 4 contiguous i per (si) -> 8 B stores
            #pragma unroll
            for (int sj = 0; sj < 4; sj++) {
                int j = j0 + jq + sj * 16 + l16;
                float bn = bnorm[(long)batch * SEQM + j];
                unsigned short* drow = Dt + (long)j * SEQN;
                #pragma unroll
                for (int si = 0; si < 4; si++) {
                    int i = i0 + iq + si * 16 + q * 4;
                    float4 an = *(const float4*)&anorm[(long)batch * SEQN + i];
                    ushort4 pack;
                    pack.x = bf16_rne((an.x + bn - 2.0f * acc[si][sj][0]) * LOG2E);
                    pack.y = bf16_rne((an.y + bn - 2.0f * acc[si][sj][1]) * LOG2E);
                    pack.z = bf16_rne((an.z + bn - 2.0f * acc[si][sj][2]) * LOG2E);
                    pack.w = bf16_rne((an.w + bn - 2.0f * acc[si][sj][3]) * LOG2E);
                    *(ushort4*)(drow + i) = pack;
                }
            }
        }
    }
    __syncthreads();                                 // Dt visible to wave 0
    if (wave != 0) return;

    // ---- Phase B: DP (round-6 body, b == batch) ----
    const unsigned short* __restrict__ dtb = Dt + 6 * t;   // t = lane 0..63

    float prev[6];
    #pragma unroll
    for (int r = 0; r < 6; r++) prev[r] = KINF2;

    uint3 dslot[4];
    float dadd[4];
    #pragma unroll
    for (int qq = 0; qq < 4; qq++) {
        int c0 = qq - 2 * t;
        int cc = c0 < 0 ? 0 : c0;
        dslot[qq] = *(const uint3*)(dtb + (long)cc * SEQN);
        dadd[qq]  = ((unsigned)c0 < (unsigned)SEQM) ? 0.0f : KINF2;
    }

    float up_cur = KINF2, up_diag = KINF2, a_m1 = KINF2;
    float lane0_diag = 0.0f;
    const bool isl0 = (t == 0);
    int j0 = 1 - 2 * t;

#define PHASE(Q)                                                            \
    {                                                                       \
        const int j = j0 + (Q);                                             \
        uint3 w = dslot[Q];                                                 \
        float da = dadd[Q];                                                 \
        float d[6];                                                         \
        d[0] = __uint_as_float(w.x << 16)          + da;                    \
        d[1] = __uint_as_float(w.x & 0xFFFF0000u)  + da;                    \
        d[2] = __uint_as_float(w.y << 16)          + da;                    \
        d[3] = __uint_as_float(w.y & 0xFFFF0000u)  + da;                    \
        d[4] = __uint_as_float(w.z << 16)          + da;                    \
        d[5] = __uint_as_float(w.z & 0xFFFF0000u)  + da;                    \
        {                                                                   \
            int cn = j + 3;                                                 \
            int cc = cn < 0 ? 0 : (cn > (SEQM - 1) ? (SEQM - 1) : cn);      \
            dslot[Q] = *(const uint3*)(dtb + (long)cc * SEQN);              \
            dadd[Q]  = ((unsigned)cn < (unsigned)SEQM) ? 0.0f : KINF2;      \
        }                                                                   \
        float dg = isl0 ? lane0_diag : up_diag;                             \
        float up = isl0 ? KINF2      : up_cur;                              \
        float pm[6], Sp[6], dpm[6];                                         \
        _Pragma("unroll")                                                   \
        for (int r = 0; r < 6; r++) {                                       \
            float dgr = (r == 0) ? dg : prev[r - 1];                        \
            float lf  = prev[r];                                            \
            float mn = fminf(dgr, lf), mx = fmaxf(dgr, lf);                 \
            pm[r]  = mn;                                                    \
            Sp[r]  = EXP2F(mn - mx) + 1.0f;                                 \
            dpm[r] = d[r] + mn;                                             \
        }                                                                   \
        _Pragma("unroll")                                                   \
        for (int r = 0; r < 6; r++) {                                       \
            float delta = up - pm[r];                                       \
            float x  = fminf(delta, -delta);                                \
            float fm = fminf(delta, 0.0f);                                  \
            float e  = EXP2F(x);                                            \
            float tn = __builtin_fmaf(e, Sp[r], 1.0f);                      \
            float tp = Sp[r] + e;                                           \
            float tot = (delta < 0.0f) ? tn : tp;                           \
            float v = (dpm[r] + fm) - LOG2F(tot);                           \
            prev[r] = v; up = v;                                            \
        }                                                                   \
        float bottom = prev[5];                                             \
        up_diag = up_cur; up_cur = a_m1;                                    \
        a_m1 = __shfl_up(bottom, 1, 64);                                    \
        lane0_diag = KINF2;                                                 \
    }

    for (int blk = 0; blk < 127; blk++) {            // 508 phases
        PHASE(0) PHASE(1) PHASE(2) PHASE(3)
        j0 += 4;
    }
    PHASE(0) PHASE(1)                                // phases 509, 510
#undef PHASE

    if (t == 63) out[batch] = prev[5] * LN2;
}

// ---------------------------------------------------------------------------
extern "C" void kernel_launch(void* const* d_in, const int* in_sizes, int n_in,
                              void* d_out, int out_size, void* d_ws, size_t ws_size,
                              hipStream_t stream) {
    (void)in_sizes; (void)n_in; (void)out_size; (void)ws_size;
    const float* a = (const float*)d_in[0];
    const float* b = (const float*)d_in[1];
    float* out = (float*)d_out;

    // ws layout: Dt | a16 | b16 | anorm | bnorm  -> 63,307,776 bytes total
    unsigned short* Dmat = (unsigned short*)d_ws;                 // 18,874,368 elems
    unsigned short* a16  = Dmat + (long)BATCH * SEQN * SEQM;      //  6,291,456 elems
    unsigned short* b16  = a16  + (long)BATCH * SEQN * DIM;       //  6,291,456 elems
    float* anorm = (float*)(b16 + (long)BATCH * SEQM * DIM);
    float* bnorm = anorm + (long)BATCH * SEQN;

    prep_kernel<<<dim3(24576), dim3(256), 0, stream>>>(a, b, a16, b16, anorm, bnorm);
    fused_kernel<<<dim3(BATCH), dim3(256), 0, stream>>>(
        a16, b16, anorm, bnorm, Dmat, out);
}

// Round 9
// 236.614 us; speedup vs baseline: 1.1117x; 1.1117x over previous
//
#include <hip/hip_runtime.h>
#include <stdint.h>

// Problem constants (fixed by the reference setup_inputs)
#define BATCH 128
#define SEQN  384
#define SEQM  384
#define DIM   128
#define KINF   1000000.0f                 // reference pseudo-infinity (nat units)
#define LOG2E  1.4426950408889634f
#define LN2    0.6931471805599453f
#define KINF2  (KINF * LOG2E)             // pseudo-infinity in base-2-scaled units

// hardware base-2 transcendentals (v_exp_f32 / v_log_f32)
#define EXP2F(x) __builtin_amdgcn_exp2f(x)
#define LOG2F(x) __builtin_amdgcn_logf(x)

typedef __attribute__((ext_vector_type(8))) short bf16x8;   // 8 bf16 = 4 VGPRs (MFMA A/B frag)
typedef __attribute__((ext_vector_type(4))) float f32x4;    // MFMA C/D frag

__device__ __forceinline__ unsigned short bf16_rne(float x) {
    uint32_t u = __float_as_uint(x);
    u += 0x7FFFu + ((u >> 16) & 1u);
    return (unsigned short)(u >> 16);
}
__device__ __forceinline__ uint32_t bf16_pair(float x, float y) {
    uint32_t ux = __float_as_uint(x); ux += 0x7FFFu + ((ux >> 16) & 1u);
    uint32_t uy = __float_as_uint(y); uy += 0x7FFFu + ((uy >> 16) & 1u);
    return (ux >> 16) | (uy & 0xFFFF0000u);
}

// ---------------------------------------------------------------------------
// Kernel 1: batched tile GEMM, fp32 inputs, NO prep pass.
// Dt[b][j][i] = (|a_i|^2 + |b_j|^2 - 2 a_i.b_j) * LOG2E, stored bf16.
// 128x128 tile / 256-thread block.  Staging loads fp32, converts to bf16
// (RNE) into swizzled LDS, and computes fp32 row norms on the fly via a
// width-16 shuffle reduction (each pass covers one full 128-elem row per
// 16-lane group).  MFMA body identical to round 7 (passing).
// ---------------------------------------------------------------------------
__global__ __launch_bounds__(256) void gemm_kernel(
        const float* __restrict__ A, const float* __restrict__ B,
        unsigned short* __restrict__ DtG) {
    __shared__ unsigned short lds[2][128][128];      // 64 KB: [0]=A(i) [1]=B(j)
    __shared__ float normA[128], normB[128];         // 1 KB
    const int batch = blockIdx.z;
    const int i0 = blockIdx.x * 128;                 // a-row tile
    const int j0 = blockIdx.y * 128;                 // b-row tile
    const int t  = threadIdx.x;

    const float* __restrict__ asrc = A + ((long)batch * SEQN + i0) * DIM;
    const float* __restrict__ bsrc = B + ((long)batch * SEQM + j0) * DIM;

    // stage + convert + norms: 8 passes x 256 thr x 8 elems (fp32)
    #pragma unroll
    for (int p = 0; p < 8; p++) {
        int e   = p * 2048 + t * 8;                  // element index in tile
        int row = e >> 7;                            // 0..127 (= p*16 + t/16)
        int grp = (e >> 3) & 15;                     // 8-elem group
        float4 a0 = *(const float4*)(asrc + e);
        float4 a1 = *(const float4*)(asrc + e + 4);
        float4 b0 = *(const float4*)(bsrc + e);
        float4 b1 = *(const float4*)(bsrc + e + 4);
        int sw = (grp ^ (row & 15)) * 8;             // bank swizzle
        uint4 va, vb;
        va.x = bf16_pair(a0.x, a0.y); va.y = bf16_pair(a0.z, a0.w);
        va.z = bf16_pair(a1.x, a1.y); va.w = bf16_pair(a1.z, a1.w);
        vb.x = bf16_pair(b0.x, b0.y); vb.y = bf16_pair(b0.z, b0.w);
        vb.z = bf16_pair(b1.x, b1.y); vb.w = bf16_pair(b1.z, b1.w);
        *(uint4*)&lds[0][row][sw] = va;
        *(uint4*)&lds[1][row][sw] = vb;
        // fp32 norms: 16 adjacent lanes hold the full 128-elem row
        float sa = a0.x*a0.x + a0.y*a0.y + a0.z*a0.z + a0.w*a0.w
                 + a1.x*a1.x + a1.y*a1.y + a1.z*a1.z + a1.w*a1.w;
        float sb = b0.x*b0.x + b0.y*b0.y + b0.z*b0.z + b0.w*b0.w
                 + b1.x*b1.x + b1.y*b1.y + b1.z*b1.z + b1.w*b1.w;
        #pragma unroll
        for (int off = 8; off > 0; off >>= 1) {
            sa += __shfl_down(sa, off, 16);
            sb += __shfl_down(sb, off, 16);
        }
        if ((t & 15) == 0) { normA[row] = sa; normB[row] = sb; }
    }
    __syncthreads();

    const int wave = t >> 6, lane = t & 63;
    const int iq = (wave & 1) * 64;                  // wave quadrant
    const int jq = (wave >> 1) * 64;
    const int l16 = lane & 15, q = lane >> 4;

    f32x4 acc[4][4] = {};                            // [si (i-dir)][sj (j-dir)]
    #pragma unroll
    for (int kk = 0; kk < 4; kk++) {                 // K = 4 * 32
        bf16x8 af[4], bfr[4];
        #pragma unroll
        for (int s = 0; s < 4; s++) {
            int arow = iq + s * 16 + l16;
            af[s]  = *(const bf16x8*)&lds[0][arow][((kk * 4 + q) ^ (arow & 15)) * 8];
            int brow = jq + s * 16 + l16;
            bfr[s] = *(const bf16x8*)&lds[1][brow][((kk * 4 + q) ^ (brow & 15)) * 8];
        }
        #pragma unroll
        for (int si = 0; si < 4; si++)
            #pragma unroll
            for (int sj = 0; sj < 4; sj++)
                acc[si][sj] = __builtin_amdgcn_mfma_f32_16x16x32_bf16(
                                  af[si], bfr[sj], acc[si][sj], 0, 0, 0);
    }

    // epilogue: col j per lane; rows i contiguous per si -> 8 B stores
    unsigned short* __restrict__ Dt = DtG + (long)batch * SEQM * SEQN;
    #pragma unroll
    for (int sj = 0; sj < 4; sj++) {
        int j = j0 + jq + sj * 16 + l16;
        float bn = normB[jq + sj * 16 + l16];
        unsigned short* drow = Dt + (long)j * SEQN;
        #pragma unroll
        for (int si = 0; si < 4; si++) {
            int i = i0 + iq + si * 16 + q * 4;
            float4 an = *(const float4*)&normA[iq + si * 16 + q * 4];
            ushort4 pack;
            pack.x = bf16_rne((an.x + bn - 2.0f * acc[si][sj][0]) * LOG2E);
            pack.y = bf16_rne((an.y + bn - 2.0f * acc[si][sj][1]) * LOG2E);
            pack.z = bf16_rne((an.z + bn - 2.0f * acc[si][sj][2]) * LOG2E);
            pack.w = bf16_rne((an.w + bn - 2.0f * acc[si][sj][3]) * LOG2E);
            *(ushort4*)(drow + i) = pack;
        }
    }
}

// ---------------------------------------------------------------------------
// Kernel 2: soft-DTW DP (round-6 body, unchanged — passing at 129.5 us).
// ---------------------------------------------------------------------------
__global__ __launch_bounds__(64) void dtw_kernel(
        const unsigned short* __restrict__ Dt, float* __restrict__ out) {
    const int b = blockIdx.x;
    const int t = threadIdx.x;                       // lane 0..63
    const unsigned short* __restrict__ dtb =
        Dt + (long)b * SEQM * SEQN + 6 * t;

    float prev[6];
    #pragma unroll
    for (int r = 0; r < 6; r++) prev[r] = KINF2;

    uint3 dslot[4];
    float dadd[4];
    #pragma unroll
    for (int q = 0; q < 4; q++) {
        int c0 = q - 2 * t;
        int cc = c0 < 0 ? 0 : c0;
        dslot[q] = *(const uint3*)(dtb + (long)cc * SEQN);
        dadd[q]  = ((unsigned)c0 < (unsigned)SEQM) ? 0.0f : KINF2;
    }

    float up_cur = KINF2, up_diag = KINF2, a_m1 = KINF2;
    float lane0_diag = 0.0f;
    const bool isl0 = (t == 0);
    int j0 = 1 - 2 * t;

#define PHASE(Q)                                                            \
    {                                                                       \
        const int j = j0 + (Q);                                             \
        uint3 w = dslot[Q];                                                 \
        float da = dadd[Q];                                                 \
        float d[6];                                                         \
        d[0] = __uint_as_float(w.x << 16)          + da;                    \
        d[1] = __uint_as_float(w.x & 0xFFFF0000u)  + da;                    \
        d[2] = __uint_as_float(w.y << 16)          + da;                    \
        d[3] = __uint_as_float(w.y & 0xFFFF0000u)  + da;                    \
        d[4] = __uint_as_float(w.z << 16)          + da;                    \
        d[5] = __uint_as_float(w.z & 0xFFFF0000u)  + da;                    \
        {                                                                   \
            int cn = j + 3;                                                 \
            int cc = cn < 0 ? 0 : (cn > (SEQM - 1) ? (SEQM - 1) : cn);      \
            dslot[Q] = *(const uint3*)(dtb + (long)cc * SEQN);              \
            dadd[Q]  = ((unsigned)cn < (unsigned)SEQM) ? 0.0f : KINF2;      \
        }                                                                   \
        float dg = isl0 ? lane0_diag : up_diag;                             \
        float up = isl0 ? KINF2      : up_cur;                              \
        float pm[6], Sp[6], dpm[6];                                         \
        _Pragma("unroll")                                                   \
        for (int r = 0; r < 6; r++) {                                       \
            float dgr = (r == 0) ? dg : prev[r - 1];                        \
            float lf  = prev[r];                                            \
            float mn = fminf(dgr, lf), mx = fmaxf(dgr, lf);                 \
            pm[r]  = mn;                                                    \
            Sp[r]  = EXP2F(mn - mx) + 1.0f;                                 \
            dpm[r] = d[r] + mn;                                             \
        }                                                                   \
        _Pragma("unroll")                                                   \
        for (int r = 0; r < 6; r++) {                                       \
            float delta = up - pm[r];                                       \
            float x  = fminf(delta, -delta);                                \
            float fm = fminf(delta, 0.0f);                                  \
            float e  = EXP2F(x);                                            \
            float tn = __builtin_fmaf(e, Sp[r], 1.0f);                      \
            float tp = Sp[r] + e;                                           \
            float tot = (delta < 0.0f) ? tn : tp;                           \
            float v = (dpm[r] + fm) - LOG2F(tot);                           \
            prev[r] = v; up = v;                                            \
        }                                                                   \
        float bottom = prev[5];                                             \
        up_diag = up_cur; up_cur = a_m1;                                    \
        a_m1 = __shfl_up(bottom, 1, 64);                                    \
        lane0_diag = KINF2;                                                 \
    }

    for (int blk = 0; blk < 127; blk++) {            // 508 phases
        PHASE(0) PHASE(1) PHASE(2) PHASE(3)
        j0 += 4;
    }
    PHASE(0) PHASE(1)                                // phases 509, 510
#undef PHASE

    if (t == 63) out[b] = prev[5] * LN2;
}

// ---------------------------------------------------------------------------
extern "C" void kernel_launch(void* const* d_in, const int* in_sizes, int n_in,
                              void* d_out, int out_size, void* d_ws, size_t ws_size,
                              hipStream_t stream) {
    (void)in_sizes; (void)n_in; (void)out_size; (void)ws_size;
    const float* a = (const float*)d_in[0];
    const float* b = (const float*)d_in[1];
    float* out = (float*)d_out;

    // ws layout: Dt only -> 37,748,736 bytes
    unsigned short* Dmat = (unsigned short*)d_ws;

    gemm_kernel<<<dim3(SEQN / 128, SEQM / 128, BATCH), dim3(256), 0, stream>>>(
        a, b, Dmat);
    dtw_kernel<<<dim3(BATCH), dim3(64), 0, stream>>>(Dmat, out);
}

// Round 10
// 231.254 us; speedup vs baseline: 1.1375x; 1.0232x over previous
//
#include <hip/hip_runtime.h>
#include <stdint.h>

// Problem constants (fixed by the reference setup_inputs)
#define BATCH 128
#define SEQN  384
#define SEQM  384
#define DIM   128
#define KINF   1000000.0f                 // reference pseudo-infinity (nat units)
#define LOG2E  1.4426950408889634f
#define LN2    0.6931471805599453f
#define KINF2  (KINF * LOG2E)             // pseudo-infinity in base-2-scaled units
#define NCOLS  388                        // 384 D-cols + 4 baked-KINF2 pad cols

// hardware base-2 transcendentals (v_exp_f32 / v_log_f32)
#define EXP2F(x) __builtin_amdgcn_exp2f(x)
#define LOG2F(x) __builtin_amdgcn_logf(x)

typedef __attribute__((ext_vector_type(8))) short bf16x8;   // 8 bf16 = 4 VGPRs (MFMA A/B frag)
typedef __attribute__((ext_vector_type(4))) float f32x4;    // MFMA C/D frag

__device__ __forceinline__ unsigned short bf16_rne(float x) {
    uint32_t u = __float_as_uint(x);
    u += 0x7FFFu + ((u >> 16) & 1u);
    return (unsigned short)(u >> 16);
}
__device__ __forceinline__ uint32_t bf16_pair(float x, float y) {
    uint32_t ux = __float_as_uint(x); ux += 0x7FFFu + ((ux >> 16) & 1u);
    uint32_t uy = __float_as_uint(y); uy += 0x7FFFu + ((uy >> 16) & 1u);
    return (ux >> 16) | (uy & 0xFFFF0000u);
}

// ---------------------------------------------------------------------------
// Kernel 1: batched tile GEMM, fp32 inputs (round-9 body, passing).
// Dt[b][c][i] = (|a_i|^2 + |b_c|^2 - 2 a_i.b_c) * LOG2E, bf16; plus 4 pad
// columns c = 384..387 baked to KINF2 (INF-flow right edge for the DP).
// ---------------------------------------------------------------------------
__global__ __launch_bounds__(256) void gemm_kernel(
        const float* __restrict__ A, const float* __restrict__ B,
        unsigned short* __restrict__ DtG) {
    __shared__ unsigned short lds[2][128][128];      // 64 KB: [0]=A(i) [1]=B(j)
    __shared__ float normA[128], normB[128];         // 1 KB
    const int batch = blockIdx.z;
    const int i0 = blockIdx.x * 128;                 // a-row tile
    const int j0 = blockIdx.y * 128;                 // b-row tile
    const int t  = threadIdx.x;

    const float* __restrict__ asrc = A + ((long)batch * SEQN + i0) * DIM;
    const float* __restrict__ bsrc = B + ((long)batch * SEQM + j0) * DIM;

    // stage + convert + norms: 8 passes x 256 thr x 8 elems (fp32)
    #pragma unroll
    for (int p = 0; p < 8; p++) {
        int e   = p * 2048 + t * 8;
        int row = e >> 7;
        int grp = (e >> 3) & 15;
        float4 a0 = *(const float4*)(asrc + e);
        float4 a1 = *(const float4*)(asrc + e + 4);
        float4 b0 = *(const float4*)(bsrc + e);
        float4 b1 = *(const float4*)(bsrc + e + 4);
        int sw = (grp ^ (row & 15)) * 8;
        uint4 va, vb;
        va.x = bf16_pair(a0.x, a0.y); va.y = bf16_pair(a0.z, a0.w);
        va.z = bf16_pair(a1.x, a1.y); va.w = bf16_pair(a1.z, a1.w);
        vb.x = bf16_pair(b0.x, b0.y); vb.y = bf16_pair(b0.z, b0.w);
        vb.z = bf16_pair(b1.x, b1.y); vb.w = bf16_pair(b1.z, b1.w);
        *(uint4*)&lds[0][row][sw] = va;
        *(uint4*)&lds[1][row][sw] = vb;
        float sa = a0.x*a0.x + a0.y*a0.y + a0.z*a0.z + a0.w*a0.w
                 + a1.x*a1.x + a1.y*a1.y + a1.z*a1.z + a1.w*a1.w;
        float sb = b0.x*b0.x + b0.y*b0.y + b0.z*b0.z + b0.w*b0.w
                 + b1.x*b1.x + b1.y*b1.y + b1.z*b1.z + b1.w*b1.w;
        #pragma unroll
        for (int off = 8; off > 0; off >>= 1) {
            sa += __shfl_down(sa, off, 16);
            sb += __shfl_down(sb, off, 16);
        }
        if ((t & 15) == 0) { normA[row] = sa; normB[row] = sb; }
    }
    __syncthreads();

    const int wave = t >> 6, lane = t & 63;
    const int iq = (wave & 1) * 64;
    const int jq = (wave >> 1) * 64;
    const int l16 = lane & 15, q = lane >> 4;

    f32x4 acc[4][4] = {};
    #pragma unroll
    for (int kk = 0; kk < 4; kk++) {
        bf16x8 af[4], bfr[4];
        #pragma unroll
        for (int s = 0; s < 4; s++) {
            int arow = iq + s * 16 + l16;
            af[s]  = *(const bf16x8*)&lds[0][arow][((kk * 4 + q) ^ (arow & 15)) * 8];
            int brow = jq + s * 16 + l16;
            bfr[s] = *(const bf16x8*)&lds[1][brow][((kk * 4 + q) ^ (brow & 15)) * 8];
        }
        #pragma unroll
        for (int si = 0; si < 4; si++)
            #pragma unroll
            for (int sj = 0; sj < 4; sj++)
                acc[si][sj] = __builtin_amdgcn_mfma_f32_16x16x32_bf16(
                                  af[si], bfr[sj], acc[si][sj], 0, 0, 0);
    }

    unsigned short* __restrict__ Dt = DtG + (long)batch * NCOLS * SEQN;
    #pragma unroll
    for (int sj = 0; sj < 4; sj++) {
        int j = j0 + jq + sj * 16 + l16;
        float bn = normB[jq + sj * 16 + l16];
        unsigned short* drow = Dt + (long)j * SEQN;
        #pragma unroll
        for (int si = 0; si < 4; si++) {
            int i = i0 + iq + si * 16 + q * 4;
            float4 an = *(const float4*)&normA[iq + si * 16 + q * 4];
            ushort4 pack;
            pack.x = bf16_rne((an.x + bn - 2.0f * acc[si][sj][0]) * LOG2E);
            pack.y = bf16_rne((an.y + bn - 2.0f * acc[si][sj][1]) * LOG2E);
            pack.z = bf16_rne((an.z + bn - 2.0f * acc[si][sj][2]) * LOG2E);
            pack.w = bf16_rne((an.w + bn - 2.0f * acc[si][sj][3]) * LOG2E);
            *(ushort4*)(drow + i) = pack;
        }
    }

    // bake pad columns c = 384..387 (KINF2) for this block's i-range
    if (blockIdx.y == 0) {
        uint32_t pv = bf16_pair(KINF2, KINF2);
        int c = 384 + (t >> 6);
        int i = i0 + ((t & 63) << 1);
        *(uint32_t*)(Dt + (long)c * SEQN + i) = pv;
    }
}

// ---------------------------------------------------------------------------
// Kernel 2: soft-DTW DP, TWO COLUMNS PER PHASE (255 phases vs 510).
// One wave per batch; lane t owns rows 6t+1..6t+6; phase p computes cols
// j = 2p-2t+1 and j+1 (12-cell serial chain).  Per-phase overhead (shuffle
// glue, unpack, refill, loop) now amortizes over 2 columns.  INF-flow:
// right edge via baked KINF2 pad cols (no per-read masking); left edge via
// junk-cell propagation (values stay >= KINF2 - O(50k), i.e. INF-like, and
// the pm-junk/up-real softmin case reduces EXACTLY to v = d + up).
// Neighbor bottoms for cols (j, j+1) are produced by lane t-1 in its
// previous phase -> 1-phase shuffle slack.
// ---------------------------------------------------------------------------
__global__ __launch_bounds__(64) void dtw_kernel(
        const unsigned short* __restrict__ Dt, float* __restrict__ out) {
    const int b = blockIdx.x;
    const int t = threadIdx.x;                       // lane 0..63
    const unsigned short* __restrict__ dtb =
        Dt + (long)b * NCOLS * SEQN + 6 * t;

    float prev[6];
    #pragma unroll
    for (int r = 0; r < 6; r++) prev[r] = KINF2;

    // raw D FIFO: slot q holds D column (c0base + q), c0base = -2t + 4k
    uint3 dslot[4];
    #pragma unroll
    for (int q = 0; q < 4; q++) {
        int c = q - 2 * t;
        int cc = c < 0 ? 0 : c;                      // clamp low (< 388 always)
        dslot[q] = *(const uint3*)(dtb + (long)cc * SEQN);
    }

    float rcv0 = KINF2, rcv1 = KINF2, old_diag = KINF2;
    float lane0_diag = 0.0f;                         // R[0][0]; KINF2 afterwards
    const bool isl0 = (t == 0);
    int c0 = -2 * t;                                 // D-col of this phase's colA

#define UNPACK(d, w)                                                        \
    d[0] = __uint_as_float(w.x << 16);                                      \
    d[1] = __uint_as_float(w.x & 0xFFFF0000u);                              \
    d[2] = __uint_as_float(w.y << 16);                                      \
    d[3] = __uint_as_float(w.y & 0xFFFF0000u);                              \
    d[4] = __uint_as_float(w.z << 16);                                      \
    d[5] = __uint_as_float(w.z & 0xFFFF0000u);

#define COLPASS(dX, diag0, upseed, LEFT, NEWV)                              \
    {                                                                       \
        float pm[6], Sp[6], dpm[6];                                         \
        _Pragma("unroll")                                                   \
        for (int r = 0; r < 6; r++) {                                       \
            float dgr = (r == 0) ? (diag0) : LEFT[r - 1];                   \
            float lf  = LEFT[r];                                            \
            float mn = fminf(dgr, lf), mx = fmaxf(dgr, lf);                 \
            pm[r]  = mn;                                                    \
            Sp[r]  = EXP2F(mn - mx) + 1.0f;                                 \
            dpm[r] = dX[r] + mn;                                            \
        }                                                                   \
        float up = (upseed);                                                \
        _Pragma("unroll")                                                   \
        for (int r = 0; r < 6; r++) {                                       \
            float delta = up - pm[r];                                       \
            float x  = fminf(delta, -delta);                                \
            float fm = fminf(delta, 0.0f);                                  \
            float e  = EXP2F(x);                                            \
            float tn = __builtin_fmaf(e, Sp[r], 1.0f);                      \
            float tp = Sp[r] + e;                                           \
            float tot = (delta < 0.0f) ? tn : tp;                           \
            float v = (dpm[r] + fm) - LOG2F(tot);                           \
            NEWV[r] = v; up = v;                                            \
        }                                                                   \
    }

#define PHASE2(Q)                                                           \
    {                                                                       \
        uint3 wA = dslot[Q];                                                \
        uint3 wB = dslot[(Q) + 1];                                          \
        {   /* refill both slots for phase p+2 (raw, no wait) */            \
            int cnA = c0 + 4;                                               \
            int ccA = cnA < 0 ? 0 : (cnA > 387 ? 387 : cnA);                \
            int cnB = c0 + 5;                                               \
            int ccB = cnB < 0 ? 0 : (cnB > 387 ? 387 : cnB);                \
            dslot[Q]       = *(const uint3*)(dtb + (long)ccA * SEQN);       \
            dslot[(Q) + 1] = *(const uint3*)(dtb + (long)ccB * SEQN);       \
        }                                                                   \
        float dA[6], dB[6];                                                 \
        UNPACK(dA, wA)                                                      \
        UNPACK(dB, wB)                                                      \
        float dgA = isl0 ? lane0_diag : old_diag;                           \
        float upA = isl0 ? KINF2 : rcv0;                                    \
        float upB = isl0 ? KINF2 : rcv1;                                    \
        float newA[6];                                                      \
        COLPASS(dA, dgA, upA, prev, newA)                                   \
        COLPASS(dB, upA, upB, newA, prev)                                   \
        old_diag = rcv1;                                                    \
        rcv0 = __shfl_up(newA[5], 1, 64);                                   \
        rcv1 = __shfl_up(prev[5], 1, 64);                                   \
        lane0_diag = KINF2;                                                 \
        c0 += 2;                                                            \
    }

    for (int pp = 0; pp < 127; pp++) {               // phases 0..253
        PHASE2(0)
        PHASE2(2)
    }
    PHASE2(0)                                        // phase 254
#undef PHASE2
#undef COLPASS
#undef UNPACK

    // lane 63, last phase colB = column 384: prev[5] = R[384][384]
    if (t == 63) out[b] = prev[5] * LN2;
}

// ---------------------------------------------------------------------------
extern "C" void kernel_launch(void* const* d_in, const int* in_sizes, int n_in,
                              void* d_out, int out_size, void* d_ws, size_t ws_size,
                              hipStream_t stream) {
    (void)in_sizes; (void)n_in; (void)out_size; (void)ws_size;
    const float* a = (const float*)d_in[0];
    const float* b = (const float*)d_in[1];
    float* out = (float*)d_out;

    // ws layout: Dt only (388 cols x 384 rows x 128 batches, bf16) = 38.1 MB
    unsigned short* Dmat = (unsigned short*)d_ws;

    gemm_kernel<<<dim3(SEQN / 128, SEQM / 128, BATCH), dim3(256), 0, stream>>>(
        a, b, Dmat);
    dtw_kernel<<<dim3(BATCH), dim3(64), 0, stream>>>(Dmat, out);
}

// Round 11
// 217.530 us; speedup vs baseline: 1.2093x; 1.0631x over previous
//
#include <hip/hip_runtime.h>
#include <stdint.h>

// Problem constants (fixed by the reference setup_inputs)
#define BATCH 128
#define SEQN  384
#define SEQM  384
#define DIM   128
#define KINF   1000000.0f                 // reference pseudo-infinity (nat units)
#define LOG2E  1.4426950408889634f
#define LN2    0.6931471805599453f
#define KINF2  (KINF * LOG2E)             // pseudo-infinity in base-2-scaled units
#define NCOLS  388                        // 384 D-cols + 4 baked-KINF2 pad cols

// hardware base-2 transcendentals (v_exp_f32 / v_log_f32)
#define EXP2F(x) __builtin_amdgcn_exp2f(x)
#define LOG2F(x) __builtin_amdgcn_logf(x)

typedef __attribute__((ext_vector_type(8))) short bf16x8;   // 8 bf16 = 4 VGPRs (MFMA A/B frag)
typedef __attribute__((ext_vector_type(4))) float f32x4;    // MFMA C/D frag

__device__ __forceinline__ unsigned short bf16_rne(float x) {
    uint32_t u = __float_as_uint(x);
    u += 0x7FFFu + ((u >> 16) & 1u);
    return (unsigned short)(u >> 16);
}
__device__ __forceinline__ uint32_t bf16_pair(float x, float y) {
    uint32_t ux = __float_as_uint(x); ux += 0x7FFFu + ((ux >> 16) & 1u);
    uint32_t uy = __float_as_uint(y); uy += 0x7FFFu + ((uy >> 16) & 1u);
    return (ux >> 16) | (uy & 0xFFFF0000u);
}

// ---------------------------------------------------------------------------
// Kernel 1: batched tile GEMM, fp32 inputs (round-9/10 body, passing).
// Dt[b][c][i] = (|a_i|^2 + |b_c|^2 - 2 a_i.b_c) * LOG2E, bf16; plus 4 pad
// columns c = 384..387 baked to KINF2 (INF-flow right edge for the DP).
// ---------------------------------------------------------------------------
__global__ __launch_bounds__(256) void gemm_kernel(
        const float* __restrict__ A, const float* __restrict__ B,
        unsigned short* __restrict__ DtG) {
    __shared__ unsigned short lds[2][128][128];      // 64 KB: [0]=A(i) [1]=B(j)
    __shared__ float normA[128], normB[128];         // 1 KB
    const int batch = blockIdx.z;
    const int i0 = blockIdx.x * 128;                 // a-row tile
    const int j0 = blockIdx.y * 128;                 // b-row tile
    const int t  = threadIdx.x;

    const float* __restrict__ asrc = A + ((long)batch * SEQN + i0) * DIM;
    const float* __restrict__ bsrc = B + ((long)batch * SEQM + j0) * DIM;

    // stage + convert + norms: 8 passes x 256 thr x 8 elems (fp32)
    #pragma unroll
    for (int p = 0; p < 8; p++) {
        int e   = p * 2048 + t * 8;
        int row = e >> 7;
        int grp = (e >> 3) & 15;
        float4 a0 = *(const float4*)(asrc + e);
        float4 a1 = *(const float4*)(asrc + e + 4);
        float4 b0 = *(const float4*)(bsrc + e);
        float4 b1 = *(const float4*)(bsrc + e + 4);
        int sw = (grp ^ (row & 15)) * 8;
        uint4 va, vb;
        va.x = bf16_pair(a0.x, a0.y); va.y = bf16_pair(a0.z, a0.w);
        va.z = bf16_pair(a1.x, a1.y); va.w = bf16_pair(a1.z, a1.w);
        vb.x = bf16_pair(b0.x, b0.y); vb.y = bf16_pair(b0.z, b0.w);
        vb.z = bf16_pair(b1.x, b1.y); vb.w = bf16_pair(b1.z, b1.w);
        *(uint4*)&lds[0][row][sw] = va;
        *(uint4*)&lds[1][row][sw] = vb;
        float sa = a0.x*a0.x + a0.y*a0.y + a0.z*a0.z + a0.w*a0.w
                 + a1.x*a1.x + a1.y*a1.y + a1.z*a1.z + a1.w*a1.w;
        float sb = b0.x*b0.x + b0.y*b0.y + b0.z*b0.z + b0.w*b0.w
                 + b1.x*b1.x + b1.y*b1.y + b1.z*b1.z + b1.w*b1.w;
        #pragma unroll
        for (int off = 8; off > 0; off >>= 1) {
            sa += __shfl_down(sa, off, 16);
            sb += __shfl_down(sb, off, 16);
        }
        if ((t & 15) == 0) { normA[row] = sa; normB[row] = sb; }
    }
    __syncthreads();

    const int wave = t >> 6, lane = t & 63;
    const int iq = (wave & 1) * 64;
    const int jq = (wave >> 1) * 64;
    const int l16 = lane & 15, q = lane >> 4;

    f32x4 acc[4][4] = {};
    #pragma unroll
    for (int kk = 0; kk < 4; kk++) {
        bf16x8 af[4], bfr[4];
        #pragma unroll
        for (int s = 0; s < 4; s++) {
            int arow = iq + s * 16 + l16;
            af[s]  = *(const bf16x8*)&lds[0][arow][((kk * 4 + q) ^ (arow & 15)) * 8];
            int brow = jq + s * 16 + l16;
            bfr[s] = *(const bf16x8*)&lds[1][brow][((kk * 4 + q) ^ (brow & 15)) * 8];
        }
        #pragma unroll
        for (int si = 0; si < 4; si++)
            #pragma unroll
            for (int sj = 0; sj < 4; sj++)
                acc[si][sj] = __builtin_amdgcn_mfma_f32_16x16x32_bf16(
                                  af[si], bfr[sj], acc[si][sj], 0, 0, 0);
    }

    unsigned short* __restrict__ Dt = DtG + (long)batch * NCOLS * SEQN;
    #pragma unroll
    for (int sj = 0; sj < 4; sj++) {
        int j = j0 + jq + sj * 16 + l16;
        float bn = normB[jq + sj * 16 + l16];
        unsigned short* drow = Dt + (long)j * SEQN;
        #pragma unroll
        for (int si = 0; si < 4; si++) {
            int i = i0 + iq + si * 16 + q * 4;
            float4 an = *(const float4*)&normA[iq + si * 16 + q * 4];
            ushort4 pack;
            pack.x = bf16_rne((an.x + bn - 2.0f * acc[si][sj][0]) * LOG2E);
            pack.y = bf16_rne((an.y + bn - 2.0f * acc[si][sj][1]) * LOG2E);
            pack.z = bf16_rne((an.z + bn - 2.0f * acc[si][sj][2]) * LOG2E);
            pack.w = bf16_rne((an.w + bn - 2.0f * acc[si][sj][3]) * LOG2E);
            *(ushort4*)(drow + i) = pack;
        }
    }

    // bake pad columns c = 384..387 (KINF2) for this block's i-range
    if (blockIdx.y == 0) {
        uint32_t pv = bf16_pair(KINF2, KINF2);
        int c = 384 + (t >> 6);
        int i = i0 + ((t & 63) << 1);
        *(uint32_t*)(Dt + (long)c * SEQN + i) = pv;
    }
}

// ---------------------------------------------------------------------------
// Kernel 2: soft-DTW DP, EXP-DOMAIN LINEAR-RECURRENCE chain.
// Same skew-2 / two-columns-per-phase structure and INF-flow as round 10
// (passing), but the per-cell softmin is restructured EXACTLY as:
//   m3  = min3(v_diag, v_left, B_{r-1})          (B = off-chain base proxy)
//   B_r = d_r + m3
//   F_r = exp2(m3 - B_{r-1}) * F_{r-1} + exp2(m3 - v_diag) + exp2(m3 - v_left)
//   v_r = B_r - log2(F_r)                        (reconstruction, slack-ful)
// Identity: F_r = exp2(B_r - v_r) -> exact softmin, no approximation.
// The serial chain is now min3+add (B) with a pipelined fma (F) behind it,
// instead of sub->exp2->fma->sel->log2 (~100 cyc/cell -> ~10 cyc/cell);
// all exp2 args are <= 0 (no overflow) and F in [1, ~1500] (up-seed is an
// exact v, so the base-vs-v drift is bounded by 6*log2(3) per pass).
// ---------------------------------------------------------------------------
__global__ __launch_bounds__(64) void dtw_kernel(
        const unsigned short* __restrict__ Dt, float* __restrict__ out) {
    const int b = blockIdx.x;
    const int t = threadIdx.x;                       // lane 0..63
    const unsigned short* __restrict__ dtb =
        Dt + (long)b * NCOLS * SEQN + 6 * t;

    float prev[6];                                   // prev column's v (exact)
    #pragma unroll
    for (int r = 0; r < 6; r++) prev[r] = KINF2;

    // raw D FIFO: slot q holds D column (c0 + q)
    uint3 dslot[4];
    #pragma unroll
    for (int q = 0; q < 4; q++) {
        int c = q - 2 * t;
        int cc = c < 0 ? 0 : c;                      // clamp low (< 388 always)
        dslot[q] = *(const uint3*)(dtb + (long)cc * SEQN);
    }

    float rcv0 = KINF2, rcv1 = KINF2, old_diag = KINF2;
    float lane0_diag = 0.0f;                         // R[0][0]; KINF2 afterwards
    const bool isl0 = (t == 0);
    int c0 = -2 * t;                                 // D-col of this phase's colA

#define UNPACK(d, w)                                                        \
    d[0] = __uint_as_float(w.x << 16);                                      \
    d[1] = __uint_as_float(w.x & 0xFFFF0000u);                              \
    d[2] = __uint_as_float(w.y << 16);                                      \
    d[3] = __uint_as_float(w.y & 0xFFFF0000u);                              \
    d[4] = __uint_as_float(w.z << 16);                                      \
    d[5] = __uint_as_float(w.z & 0xFFFF0000u);

#define COLPASS(dX, diag0, upseed, LEFTV, NEWV)                             \
    {                                                                       \
        float Bp = (upseed), Fp = 1.0f;                                     \
        float Bv[6], Fv[6];                                                 \
        _Pragma("unroll")                                                   \
        for (int r = 0; r < 6; r++) {                                       \
            float vd = (r == 0) ? (diag0) : LEFTV[r - 1];                   \
            float vl = LEFTV[r];                                            \
            float m3 = fminf(fminf(vd, vl), Bp);     /* v_min3_f32 */       \
            float al = EXP2F(m3 - Bp);                                      \
            float be = EXP2F(m3 - vd) + EXP2F(m3 - vl);                     \
            float Fr = __builtin_fmaf(al, Fp, be);                          \
            float Br = dX[r] + m3;                                          \
            Bv[r] = Br; Fv[r] = Fr;                                         \
            Bp = Br; Fp = Fr;                                               \
        }                                                                   \
        _Pragma("unroll")                                                   \
        for (int r = 0; r < 6; r++)                                         \
            NEWV[r] = Bv[r] - LOG2F(Fv[r]);                                 \
    }

#define PHASE2(Q)                                                           \
    {                                                                       \
        uint3 wA = dslot[Q];                                                \
        uint3 wB = dslot[(Q) + 1];                                          \
        {   /* refill both slots for phase p+2 (raw, no wait) */            \
            int cnA = c0 + 4;                                               \
            int ccA = cnA < 0 ? 0 : (cnA > 387 ? 387 : cnA);                \
            int cnB = c0 + 5;                                               \
            int ccB = cnB < 0 ? 0 : (cnB > 387 ? 387 : cnB);                \
            dslot[Q]       = *(const uint3*)(dtb + (long)ccA * SEQN);       \
            dslot[(Q) + 1] = *(const uint3*)(dtb + (long)ccB * SEQN);       \
        }                                                                   \
        float dA[6], dB[6];                                                 \
        UNPACK(dA, wA)                                                      \
        UNPACK(dB, wB)                                                      \
        float dgA = isl0 ? lane0_diag : old_diag;                           \
        float upA = isl0 ? KINF2 : rcv0;                                    \
        float upB = isl0 ? KINF2 : rcv1;                                    \
        float newA[6];                                                      \
        COLPASS(dA, dgA, upA, prev, newA)                                   \
        COLPASS(dB, upA, upB, newA, prev)                                   \
        old_diag = rcv1;                                                    \
        rcv0 = __shfl_up(newA[5], 1, 64);                                   \
        rcv1 = __shfl_up(prev[5], 1, 64);                                   \
        lane0_diag = KINF2;                                                 \
        c0 += 2;                                                            \
    }

    for (int pp = 0; pp < 127; pp++) {               // phases 0..253
        PHASE2(0)
        PHASE2(2)
    }
    PHASE2(0)                                        // phase 254
#undef PHASE2
#undef COLPASS
#undef UNPACK

    // lane 63, last phase colB = column 384: prev[5] = R[384][384]
    if (t == 63) out[b] = prev[5] * LN2;
}

// ---------------------------------------------------------------------------
extern "C" void kernel_launch(void* const* d_in, const int* in_sizes, int n_in,
                              void* d_out, int out_size, void* d_ws, size_t ws_size,
                              hipStream_t stream) {
    (void)in_sizes; (void)n_in; (void)out_size; (void)ws_size;
    const float* a = (const float*)d_in[0];
    const float* b = (const float*)d_in[1];
    float* out = (float*)d_out;

    // ws layout: Dt only (388 cols x 384 rows x 128 batches, bf16) = 38.1 MB
    unsigned short* Dmat = (unsigned short*)d_ws;

    gemm_kernel<<<dim3(SEQN / 128, SEQM / 128, BATCH), dim3(256), 0, stream>>>(
        a, b, Dmat);
    dtw_kernel<<<dim3(BATCH), dim3(64), 0, stream>>>(Dmat, out);
}